// Round 20
// baseline (260.966 us; speedup 1.0000x reference)
//
#include <hip/hip_runtime.h>
#include <hip/hip_bf16.h>
#include <cstdint>
#include <cstddef>

#define S_LEN 2048
#define DM 1024
#define NEGV -1.0e9f

typedef __attribute__((ext_vector_type(8))) short bf16x8;
typedef __attribute__((ext_vector_type(4))) float f32x4;
typedef __attribute__((ext_vector_type(4))) unsigned short us4;
typedef __attribute__((ext_vector_type(4))) int i32x4;
typedef __attribute__((ext_vector_type(4))) unsigned int ui32x4;
typedef __attribute__((ext_vector_type(2))) unsigned int u32x2;

__device__ __forceinline__ unsigned short f2bf(float f) {
  unsigned int u = __float_as_uint(f);
  unsigned int r = (u + 0x7fffu + ((u >> 16) & 1u)) >> 16;
  return (unsigned short)r;
}

__device__ __forceinline__ unsigned int pack_bf2(float a, float b) {
  return (unsigned int)f2bf(a) | ((unsigned int)f2bf(b) << 16);
}

__device__ __forceinline__ void async_copy16(const void* g, void* l) {
  __builtin_amdgcn_global_load_lds((const __attribute__((address_space(1))) void*)g,
                                   (__attribute__((address_space(3))) void*)l, 16, 0, 0);
}

// ---------------- prep: f32->bf16 converts (6 tensors) + mask bitmask, one launch ----------------
__global__ __launch_bounds__(256) void prep_kernel(
    const float* __restrict__ q, const float* __restrict__ k, const float* __restrict__ v,
    const float* __restrict__ wq, const float* __restrict__ wk, const float* __restrict__ wv,
    const int* __restrict__ mask,
    unsigned short* __restrict__ qb, unsigned short* __restrict__ kb2, unsigned short* __restrict__ vb,
    unsigned short* __restrict__ wqb, unsigned short* __restrict__ wkb, unsigned short* __restrict__ wvb,
    unsigned int* __restrict__ mb) {
  if (blockIdx.x < 15360) {
    const int gid = blockIdx.x * 256 + threadIdx.x;
    const float* src; unsigned short* dst; int idx;
    if (gid < 3145728) {
      const int j = gid >> 20; idx = gid & 1048575;
      src = (j == 0) ? q : (j == 1) ? k : v;
      dst = (j == 0) ? qb : (j == 1) ? kb2 : vb;
    } else {
      const int g = gid - 3145728;
      const int j = g >> 18; idx = g & 262143;
      src = (j == 0) ? wq : (j == 1) ? wk : wv;
      dst = (j == 0) ? wqb : (j == 1) ? wkb : wvb;
    }
    const float4 vv = reinterpret_cast<const float4*>(src)[idx];
    us4 o;
    o[0] = f2bf(vv.x); o[1] = f2bf(vv.y); o[2] = f2bf(vv.z); o[3] = f2bf(vv.w);
    reinterpret_cast<us4*>(dst)[idx] = o;
  } else {
    const int idx = (blockIdx.x - 15360) * 256 + threadIdx.x;
    const int row = idx >> 6, w = idx & 63;
    const int* src = mask + (size_t)row * S_LEN + w * 32;
    unsigned int r = 0;
#pragma unroll
    for (int j = 0; j < 8; ++j) {
      const i32x4 vv = *(const i32x4*)(src + j * 4);
      r |= (vv[0] ? 1u : 0u) << (j * 4 + 0);
      r |= (vv[1] ? 1u : 0u) << (j * 4 + 1);
      r |= (vv[2] ? 1u : 0u) << (j * 4 + 2);
      r |= (vv[3] ? 1u : 0u) << (j * 4 + 3);
    }
    mb[(size_t)row * 64 + w] = r;
  }
}

// ---------------- projection GEMM, XCD-supertiled, PACKED epilogue (v17, passed) ----------------
__global__ __launch_bounds__(256) void proj_gemm(
    const unsigned short* __restrict__ Xq, const unsigned short* __restrict__ Wqw,
    const float* __restrict__ bq, unsigned short* __restrict__ Cq,
    const unsigned short* __restrict__ Xk, const unsigned short* __restrict__ Wkw,
    const float* __restrict__ bk, unsigned short* __restrict__ Kpk,
    const unsigned short* __restrict__ Xv, const unsigned short* __restrict__ Wvw,
    const float* __restrict__ bv, unsigned short* __restrict__ Vpk) {
  __shared__ unsigned short smem[16640];
  unsigned short* Ab = smem;
  unsigned short* Bb = smem + 8192;

  const int bid = blockIdx.x;
  const int c = bid & 7, s = bid >> 3;
  const int n0 = (s & 7) * 128;
  const int mzg = c * 12 + (s >> 3);
  const int m0 = (mzg & 31) * 128;
  const int z = mzg >> 5;

  const unsigned short* X; const unsigned short* W; const float* bias;
  if (z == 0)      { X = Xq; W = Wqw; bias = bq; }
  else if (z == 1) { X = Xk; W = Wkw; bias = bk; }
  else             { X = Xv; W = Wvw; bias = bv; }

  const int t  = threadIdx.x;
  const int wv2 = t >> 6, l = t & 63;
  const int lr = l & 15, lg = l >> 4;
  const int wr = wv2 >> 1, wc = wv2 & 1;

  const f32x4 fz = {0.f, 0.f, 0.f, 0.f};
  f32x4 acc[4][4];
#pragma unroll
  for (int m = 0; m < 4; ++m)
#pragma unroll
    for (int n = 0; n < 4; ++n) acc[m][n] = fz;

  const int srow = t >> 3;
  const int sc16 = t & 7;

  for (int kt = 0; kt < 16; ++kt) {
    const int kb = kt * 64;
#pragma unroll
    for (int it = 0; it < 4; ++it) {
      const int row = it * 32 + srow;
      const int c16 = sc16 ^ (row & 7);
      const unsigned short* gA = X + (size_t)(m0 + row) * DM + kb + c16 * 8;
      const unsigned short* gB = W + (size_t)(n0 + row) * DM + kb + c16 * 8;
      async_copy16(gA, (char*)Ab + it * 4096 + wv2 * 1024);
      async_copy16(gB, (char*)Bb + it * 4096 + wv2 * 1024);
    }
    __syncthreads();
#pragma unroll
    for (int kk = 0; kk < 2; ++kk) {
      bf16x8 af[4], bfr[4];
      const int c16 = kk * 4 + lg;
      const int sw = (c16 ^ (lr & 7)) * 16;
#pragma unroll
      for (int m = 0; m < 4; ++m) {
        const int row = wr * 64 + m * 16 + lr;
        af[m] = *(const bf16x8*)((const char*)Ab + row * 128 + sw);
      }
#pragma unroll
      for (int n = 0; n < 4; ++n) {
        const int row = wc * 64 + n * 16 + lr;
        bfr[n] = *(const bf16x8*)((const char*)Bb + row * 128 + sw);
      }
#pragma unroll
      for (int m = 0; m < 4; ++m)
#pragma unroll
        for (int n = 0; n < 4; ++n)
          acc[m][n] = __builtin_amdgcn_mfma_f32_16x16x32_bf16(af[m], bfr[n], acc[m][n], 0, 0, 0);
    }
    __syncthreads();
  }

  unsigned short* Ct = smem;
#pragma unroll
  for (int n = 0; n < 4; ++n) {
    const int ccolL = wc * 64 + n * 16 + lr;
    const float bb = bias[n0 + ccolL];
#pragma unroll
    for (int m = 0; m < 4; ++m) {
      const int crowL = wr * 64 + m * 16 + lg * 4;
#pragma unroll
      for (int j = 0; j < 4; ++j)
        Ct[(crowL + j) * 130 + ccolL] = f2bf(acc[m][n][j] + bb);
    }
  }
  __syncthreads();

  if (z == 0) {
#pragma unroll
    for (int i = 0; i < 8; ++i) {
      const int cid = i * 256 + t;
      const int row = cid >> 4, colc = cid & 15;
      const bf16x8 v8 = *(const bf16x8*)(Ct + row * 130 + colc * 8);
      *(bf16x8*)(Cq + (size_t)(m0 + row) * DM + n0 + colc * 8) = v8;
    }
  } else if (z == 1) {
    const int b = m0 >> 11;
    const int kbb = (m0 & 2047) >> 4;
    const int hb = n0 >> 6;
#pragma unroll
    for (int i = 0; i < 8; ++i) {
      const int cid = i * 256 + t;
      const int lane = cid & 63;
      const int sub = cid >> 6;
      const int chunk = sub & 1;
      const int hl = (sub >> 1) & 1;
      const int kbl = sub >> 2;
      const int row = kbl * 16 + (lane & 15);
      const int col = hl * 64 + chunk * 32 + (lane >> 4) * 8;
      const bf16x8 v8 = *(const bf16x8*)(Ct + row * 130 + col);
      unsigned short* dst = Kpk + ((size_t)((b * 16 + hb + hl) * 128 + kbb + kbl) * 2 + chunk) * 512 + lane * 8;
      *(bf16x8*)dst = v8;
    }
  } else {
    const int b = m0 >> 11;
    const int k32b = (m0 & 2047) >> 5;
    const int hb = n0 >> 6;
#pragma unroll
    for (int i = 0; i < 8; ++i) {
      const int cid = i * 256 + t;
      const int lane = cid & 63;
      const int sub = cid >> 6;
      const int n = sub & 3;
      const int hl = (sub >> 2) & 1;
      const int l32 = sub >> 3;
      const int col = hl * 64 + n * 16 + (lane & 15);
      const int rbase = l32 * 32 + (lane >> 4) * 8;
      unsigned short v8[8];
#pragma unroll
      for (int e = 0; e < 8; ++e)
        v8[e] = Ct[(rbase + e) * 130 + col];
      const int k32 = k32b + l32;
      const int wv3 = k32 >> 3, pr = (k32 >> 1) & 3, s2 = k32 & 1;
      const int blk = ((wv3 * 4 + pr) * 2 + s2) * 4 + n;
      unsigned short* dst = Vpk + ((size_t)((b * 16 + hb + hl) * 256 + blk) * 512 + lane * 8);
      *(bf16x8*)dst = *(bf16x8*)v8;
    }
  }
}

// ---------------- fused attention v20: v18 structure, L2 (non-NT) attn stores ----------------
// Single-variable A/B vs v18: plain f32x4 stores instead of nontemporal. v11's NT-vs-L2
// test predated packed K/V (loads then thrashed L2); with clean packed loads, L2
// write-combining may reach fill-kernel rates (6.7 TB/s) vs NT's ~3.7 effective.
__global__ __launch_bounds__(512, 4) void attn20_kernel(
    const unsigned short* __restrict__ Qp, const unsigned short* __restrict__ Kpk,
    const unsigned short* __restrict__ Vpk, const unsigned int* __restrict__ mbits,
    float* __restrict__ outp, float* __restrict__ attnp) {
  __shared__ float rsred[8][16];
  __shared__ float rinv16[16];
  __shared__ char uni[8][4224];

  const int bx = blockIdx.x;
  const int c  = bx & 7;
  const int s  = bx >> 3;
  const int j  = s & 3;
  const int qt = s >> 2;
  const int bh = c * 4 + j;
  const int b  = bh >> 4, h = bh & 15;
  const int q0 = qt << 4;

  const int w = threadIdx.x >> 6, l = threadIdx.x & 63;
  const int lr = l & 15, lg = l >> 4;
  const int kw0 = w << 8;

  const float scale = 0.125f;
  const f32x4 fz = {0.f, 0.f, 0.f, 0.f};

  const unsigned short* Qh = Qp + (size_t)(b * S_LEN + q0 + lr) * DM + h * 64;
  const bf16x8 qf0 = *(const bf16x8*)(Qh + lg * 8);
  const bf16x8 qf1 = *(const bf16x8*)(Qh + 32 + lg * 8);

  const unsigned short* Kw = Kpk + (size_t)((b * 16 + h) * 128 + w * 16) * 1024;

  const unsigned int* mbr = mbits + ((size_t)(b * S_LEN + q0 + lr) << 6) + (kw0 >> 5);
  const ui32x4 mwa = *(const ui32x4*)(mbr);
  const ui32x4 mwb = *(const ui32x4*)(mbr + 4);

  unsigned int pkA[16], pkB[16];
  float rs = 0.f;
#pragma unroll
  for (int i = 0; i < 16; ++i) {
    const bf16x8 ka0 = *(const bf16x8*)(Kw + i * 1024 + l * 8);
    const bf16x8 ka1 = *(const bf16x8*)(Kw + i * 1024 + 512 + l * 8);
    f32x4 sc = fz;
    sc = __builtin_amdgcn_mfma_f32_16x16x32_bf16(ka0, qf0, sc, 0, 0, 0);
    sc = __builtin_amdgcn_mfma_f32_16x16x32_bf16(ka1, qf1, sc, 0, 0, 0);
    const unsigned int wsel = (i < 8) ? mwa[i >> 1] : mwb[(i - 8) >> 1];
    const unsigned int nib = (wsel >> ((i & 1) * 16 + lg * 4)) & 15u;
    const float e0 = __expf((nib & 1u) ? sc[0] * scale : NEGV);
    const float e1 = __expf((nib & 2u) ? sc[1] * scale : NEGV);
    const float e2 = __expf((nib & 4u) ? sc[2] * scale : NEGV);
    const float e3 = __expf((nib & 8u) ? sc[3] * scale : NEGV);
    rs += (e0 + e1) + (e2 + e3);
    pkA[i] = pack_bf2(e0, e1);
    pkB[i] = pack_bf2(e2, e3);
  }
  rs += __shfl_xor(rs, 16, 64);
  rs += __shfl_xor(rs, 32, 64);
  if (l < 16) rsred[w][l] = rs;
  __syncthreads();
  if (threadIdx.x < 16) {
    float s0 = 0.f;
#pragma unroll
    for (int ww = 0; ww < 8; ++ww) s0 += rsred[ww][threadIdx.x];
    rinv16[threadIdx.x] = 1.0f / s0;
  }
  __syncthreads();

  const unsigned short* Vw = Vpk + ((size_t)(b * 16 + h) * 256 + w * 32) * 512;
  unsigned short* pbase = (unsigned short*)uni[w];

  f32x4 oacc[4];
#pragma unroll
  for (int n = 0; n < 4; ++n) oacc[n] = fz;

  // ---- PV loop: loads + LDS repack + MFMA only ----
#pragma unroll
  for (int pr = 0; pr < 4; ++pr) {
    unsigned short* pb = pbase + (pr & 1) * 1056;

    bf16x8 vbr[2][4];
#pragma unroll
    for (int s2 = 0; s2 < 2; ++s2)
#pragma unroll
      for (int n = 0; n < 4; ++n)
        vbr[s2][n] = *(const bf16x8*)(Vw + (size_t)(((pr * 2 + s2) * 4) + n) * 512 + l * 8);

#pragma unroll
    for (int s2 = 0; s2 < 2; ++s2) {
      const int wi = pr * 2 + s2;
      const u32x2 wv0 = {pkA[2 * wi],     pkB[2 * wi]};
      const u32x2 wv1 = {pkA[2 * wi + 1], pkB[2 * wi + 1]};
      *(u32x2*)(pb + lr * 66 + s2 * 32 + lg * 4) = wv0;
      *(u32x2*)(pb + lr * 66 + s2 * 32 + 16 + lg * 4) = wv1;
    }
#pragma unroll
    for (int s2 = 0; s2 < 2; ++s2) {
      const bf16x8 pa = *(const bf16x8*)(pb + lr * 66 + s2 * 32 + lg * 8);
#pragma unroll
      for (int n = 0; n < 4; ++n)
        oacc[n] = __builtin_amdgcn_mfma_f32_16x16x32_bf16(pa, vbr[s2][n], oacc[n], 0, 0, 0);
    }
  }

  // ---- store phase: 2 halves, per-wave [16][132] transpose, 2x512B per instr (L2 stores) ----
  asm volatile("s_waitcnt lgkmcnt(0)" ::: "memory");
  float rv8[8];
#pragma unroll
  for (int jj = 0; jj < 8; ++jj) rv8[jj] = rinv16[(l >> 5) + 2 * jj];
  float* attnR = attnp + (size_t)((b * 16 + h) * S_LEN + q0) * S_LEN + kw0;
#pragma unroll
  for (int sh = 0; sh < 2; ++sh) {
#pragma unroll
    for (int i8 = 0; i8 < 8; ++i8) {
      const int i = sh * 8 + i8;
      const u32x2 wv = {pkA[i], pkB[i]};
      *(u32x2*)(pbase + lr * 132 + i8 * 16 + lg * 4) = wv;
    }
    asm volatile("s_waitcnt lgkmcnt(0)" ::: "memory");
#pragma unroll
    for (int jj = 0; jj < 8; ++jj) {
      const int row = (l >> 5) + 2 * jj;
      const us4 p4 = *(const us4*)(pbase + row * 132 + (l & 31) * 4);
      const float rv = rv8[jj];
      const f32x4 st = {__uint_as_float((unsigned)p4[0] << 16) * rv,
                        __uint_as_float((unsigned)p4[1] << 16) * rv,
                        __uint_as_float((unsigned)p4[2] << 16) * rv,
                        __uint_as_float((unsigned)p4[3] << 16) * rv};
      *(f32x4*)(attnR + (size_t)row * S_LEN + sh * 128 + (l & 31) * 4) = st;
    }
    asm volatile("s_waitcnt lgkmcnt(0)" ::: "memory");
  }

  // ---- cross-wave out reduction ----
  float* outred = (float*)uni[w];
#pragma unroll
  for (int n = 0; n < 4; ++n)
#pragma unroll
    for (int jj = 0; jj < 4; ++jj)
      outred[(lg * 4 + jj) * 64 + n * 16 + lr] = oacc[n][jj];
  __syncthreads();
  if (threadIdx.x < 256) {
    const int q = threadIdx.x >> 4;
    const int d0 = (threadIdx.x & 15) * 4;
    const float rq = rinv16[q];
    float4 o = {0.f, 0.f, 0.f, 0.f};
#pragma unroll
    for (int ww = 0; ww < 8; ++ww) {
      const f32x4 sv = *(const f32x4*)((const float*)uni[ww] + q * 64 + d0);
      o.x += sv[0]; o.y += sv[1]; o.z += sv[2]; o.w += sv[3];
    }
    o.x *= rq; o.y *= rq; o.z *= rq; o.w *= rq;
    *(float4*)(outp + (size_t)(b * S_LEN + q0 + q) * DM + h * 64 + d0) = o;
  }
}

extern "C" void kernel_launch(void* const* d_in, const int* in_sizes, int n_in,
                              void* d_out, int out_size, void* d_ws, size_t ws_size,
                              hipStream_t stream) {
  const float* query = (const float*)d_in[0];
  const float* key_  = (const float*)d_in[1];
  const float* value = (const float*)d_in[2];
  const int*   mask  = (const int*)d_in[3];
  const float* Wq = (const float*)d_in[4];
  const float* bq = (const float*)d_in[5];
  const float* Wk = (const float*)d_in[6];
  const float* bk = (const float*)d_in[7];
  const float* Wv = (const float*)d_in[8];
  const float* bv = (const float*)d_in[9];

  float* outp  = (float*)d_out;
  float* attnp = outp + (size_t)2 * S_LEN * DM;

  unsigned short* ws  = (unsigned short*)d_ws;
  unsigned short* qbf = ws;
  unsigned short* kbf = qbf + 4194304;
  unsigned short* vbf = kbf + 4194304;
  unsigned short* wqb = vbf + 4194304;
  unsigned short* wkb = wqb + 1048576;
  unsigned short* wvb = wkb + 1048576;
  unsigned short* qp  = wvb + 1048576;
  unsigned short* kpk = qp + 4194304;
  unsigned short* vpk = kpk + 4194304;
  unsigned int*   mb  = (unsigned int*)(vpk + 4194304);

  prep_kernel<<<16384, 256, 0, stream>>>(query, key_, value, Wq, Wk, Wv, mask,
                                         qbf, kbf, vbf, wqb, wkb, wvb, mb);
  proj_gemm<<<768, 256, 0, stream>>>(qbf, wqb, bq, qp,
                                     kbf, wkb, bk, kpk,
                                     vbf, wvb, bv, vpk);
  attn20_kernel<<<4096, 512, 0, stream>>>(qp, kpk, vpk, mb, outp, attnp);
}

// Round 21
// 220.545 us; speedup vs baseline: 1.1833x; 1.1833x over previous
//
#include <hip/hip_runtime.h>
#include <hip/hip_bf16.h>
#include <cstdint>
#include <cstddef>

#define S_LEN 2048
#define DM 1024
#define NEGV -1.0e9f

typedef __attribute__((ext_vector_type(8))) short bf16x8;
typedef __attribute__((ext_vector_type(4))) float f32x4;
typedef __attribute__((ext_vector_type(4))) unsigned short us4;
typedef __attribute__((ext_vector_type(4))) int i32x4;
typedef __attribute__((ext_vector_type(4))) unsigned int ui32x4;
typedef __attribute__((ext_vector_type(2))) unsigned int u32x2;

__device__ __forceinline__ unsigned short f2bf(float f) {
  unsigned int u = __float_as_uint(f);
  unsigned int r = (u + 0x7fffu + ((u >> 16) & 1u)) >> 16;
  return (unsigned short)r;
}

__device__ __forceinline__ unsigned int pack_bf2(float a, float b) {
  return (unsigned int)f2bf(a) | ((unsigned int)f2bf(b) << 16);
}

__device__ __forceinline__ void async_copy16(const void* g, void* l) {
  __builtin_amdgcn_global_load_lds((const __attribute__((address_space(1))) void*)g,
                                   (__attribute__((address_space(3))) void*)l, 16, 0, 0);
}

// ---------------- prep: f32->bf16 converts (6 tensors) + mask bitmask, one launch ----------------
__global__ __launch_bounds__(256) void prep_kernel(
    const float* __restrict__ q, const float* __restrict__ k, const float* __restrict__ v,
    const float* __restrict__ wq, const float* __restrict__ wk, const float* __restrict__ wv,
    const int* __restrict__ mask,
    unsigned short* __restrict__ qb, unsigned short* __restrict__ kb2, unsigned short* __restrict__ vb,
    unsigned short* __restrict__ wqb, unsigned short* __restrict__ wkb, unsigned short* __restrict__ wvb,
    unsigned int* __restrict__ mb) {
  if (blockIdx.x < 15360) {
    const int gid = blockIdx.x * 256 + threadIdx.x;
    const float* src; unsigned short* dst; int idx;
    if (gid < 3145728) {
      const int j = gid >> 20; idx = gid & 1048575;
      src = (j == 0) ? q : (j == 1) ? k : v;
      dst = (j == 0) ? qb : (j == 1) ? kb2 : vb;
    } else {
      const int g = gid - 3145728;
      const int j = g >> 18; idx = g & 262143;
      src = (j == 0) ? wq : (j == 1) ? wk : wv;
      dst = (j == 0) ? wqb : (j == 1) ? wkb : wvb;
    }
    const float4 vv = reinterpret_cast<const float4*>(src)[idx];
    us4 o;
    o[0] = f2bf(vv.x); o[1] = f2bf(vv.y); o[2] = f2bf(vv.z); o[3] = f2bf(vv.w);
    reinterpret_cast<us4*>(dst)[idx] = o;
  } else {
    const int idx = (blockIdx.x - 15360) * 256 + threadIdx.x;
    const int row = idx >> 6, w = idx & 63;
    const int* src = mask + (size_t)row * S_LEN + w * 32;
    unsigned int r = 0;
#pragma unroll
    for (int j = 0; j < 8; ++j) {
      const i32x4 vv = *(const i32x4*)(src + j * 4);
      r |= (vv[0] ? 1u : 0u) << (j * 4 + 0);
      r |= (vv[1] ? 1u : 0u) << (j * 4 + 1);
      r |= (vv[2] ? 1u : 0u) << (j * 4 + 2);
      r |= (vv[3] ? 1u : 0u) << (j * 4 + 3);
    }
    mb[(size_t)row * 64 + w] = r;
  }
}

// ---------------- projection GEMM, XCD-supertiled, PACKED epilogue ----------------
__global__ __launch_bounds__(256) void proj_gemm(
    const unsigned short* __restrict__ Xq, const unsigned short* __restrict__ Wqw,
    const float* __restrict__ bq, unsigned short* __restrict__ Cq,
    const unsigned short* __restrict__ Xk, const unsigned short* __restrict__ Wkw,
    const float* __restrict__ bk, unsigned short* __restrict__ Kpk,
    const unsigned short* __restrict__ Xv, const unsigned short* __restrict__ Wvw,
    const float* __restrict__ bv, unsigned short* __restrict__ Vpk) {
  __shared__ unsigned short smem[16640];
  unsigned short* Ab = smem;
  unsigned short* Bb = smem + 8192;

  const int bid = blockIdx.x;
  const int c = bid & 7, s = bid >> 3;
  const int n0 = (s & 7) * 128;
  const int mzg = c * 12 + (s >> 3);
  const int m0 = (mzg & 31) * 128;
  const int z = mzg >> 5;

  const unsigned short* X; const unsigned short* W; const float* bias;
  if (z == 0)      { X = Xq; W = Wqw; bias = bq; }
  else if (z == 1) { X = Xk; W = Wkw; bias = bk; }
  else             { X = Xv; W = Wvw; bias = bv; }

  const int t  = threadIdx.x;
  const int wv2 = t >> 6, l = t & 63;
  const int lr = l & 15, lg = l >> 4;
  const int wr = wv2 >> 1, wc = wv2 & 1;

  const f32x4 fz = {0.f, 0.f, 0.f, 0.f};
  f32x4 acc[4][4];
#pragma unroll
  for (int m = 0; m < 4; ++m)
#pragma unroll
    for (int n = 0; n < 4; ++n) acc[m][n] = fz;

  const int srow = t >> 3;
  const int sc16 = t & 7;

  for (int kt = 0; kt < 16; ++kt) {
    const int kb = kt * 64;
#pragma unroll
    for (int it = 0; it < 4; ++it) {
      const int row = it * 32 + srow;
      const int c16 = sc16 ^ (row & 7);
      const unsigned short* gA = X + (size_t)(m0 + row) * DM + kb + c16 * 8;
      const unsigned short* gB = W + (size_t)(n0 + row) * DM + kb + c16 * 8;
      async_copy16(gA, (char*)Ab + it * 4096 + wv2 * 1024);
      async_copy16(gB, (char*)Bb + it * 4096 + wv2 * 1024);
    }
    __syncthreads();
#pragma unroll
    for (int kk = 0; kk < 2; ++kk) {
      bf16x8 af[4], bfr[4];
      const int c16 = kk * 4 + lg;
      const int sw = (c16 ^ (lr & 7)) * 16;
#pragma unroll
      for (int m = 0; m < 4; ++m) {
        const int row = wr * 64 + m * 16 + lr;
        af[m] = *(const bf16x8*)((const char*)Ab + row * 128 + sw);
      }
#pragma unroll
      for (int n = 0; n < 4; ++n) {
        const int row = wc * 64 + n * 16 + lr;
        bfr[n] = *(const bf16x8*)((const char*)Bb + row * 128 + sw);
      }
#pragma unroll
      for (int m = 0; m < 4; ++m)
#pragma unroll
        for (int n = 0; n < 4; ++n)
          acc[m][n] = __builtin_amdgcn_mfma_f32_16x16x32_bf16(af[m], bfr[n], acc[m][n], 0, 0, 0);
    }
    __syncthreads();
  }

  unsigned short* Ct = smem;
#pragma unroll
  for (int n = 0; n < 4; ++n) {
    const int ccolL = wc * 64 + n * 16 + lr;
    const float bb = bias[n0 + ccolL];
#pragma unroll
    for (int m = 0; m < 4; ++m) {
      const int crowL = wr * 64 + m * 16 + lg * 4;
#pragma unroll
      for (int j = 0; j < 4; ++j)
        Ct[(crowL + j) * 130 + ccolL] = f2bf(acc[m][n][j] + bb);
    }
  }
  __syncthreads();

  if (z == 0) {
#pragma unroll
    for (int i = 0; i < 8; ++i) {
      const int cid = i * 256 + t;
      const int row = cid >> 4, colc = cid & 15;
      const bf16x8 v8 = *(const bf16x8*)(Ct + row * 130 + colc * 8);
      *(bf16x8*)(Cq + (size_t)(m0 + row) * DM + n0 + colc * 8) = v8;
    }
  } else if (z == 1) {
    const int b = m0 >> 11;
    const int kbb = (m0 & 2047) >> 4;
    const int hb = n0 >> 6;
#pragma unroll
    for (int i = 0; i < 8; ++i) {
      const int cid = i * 256 + t;
      const int lane = cid & 63;
      const int sub = cid >> 6;
      const int chunk = sub & 1;
      const int hl = (sub >> 1) & 1;
      const int kbl = sub >> 2;
      const int row = kbl * 16 + (lane & 15);
      const int col = hl * 64 + chunk * 32 + (lane >> 4) * 8;
      const bf16x8 v8 = *(const bf16x8*)(Ct + row * 130 + col);
      unsigned short* dst = Kpk + ((size_t)((b * 16 + hb + hl) * 128 + kbb + kbl) * 2 + chunk) * 512 + lane * 8;
      *(bf16x8*)dst = v8;
    }
  } else {
    const int b = m0 >> 11;
    const int k32b = (m0 & 2047) >> 5;
    const int hb = n0 >> 6;
#pragma unroll
    for (int i = 0; i < 8; ++i) {
      const int cid = i * 256 + t;
      const int lane = cid & 63;
      const int sub = cid >> 6;
      const int n = sub & 3;
      const int hl = (sub >> 2) & 1;
      const int l32 = sub >> 3;
      const int col = hl * 64 + n * 16 + (lane & 15);
      const int rbase = l32 * 32 + (lane >> 4) * 8;
      unsigned short v8[8];
#pragma unroll
      for (int e = 0; e < 8; ++e)
        v8[e] = Ct[(rbase + e) * 130 + col];
      const int k32 = k32b + l32;
      const int wv3 = k32 >> 3, pr = (k32 >> 1) & 3, s2 = k32 & 1;
      const int blk = ((wv3 * 4 + pr) * 2 + s2) * 4 + n;
      unsigned short* dst = Vpk + ((size_t)((b * 16 + hb + hl) * 256 + blk) * 512 + lane * 8);
      *(bf16x8*)dst = *(bf16x8*)v8;
    }
  }
}

// ---------------- fused attention v18 (session best): NT stores, 512B segments ----------------
__global__ __launch_bounds__(512, 4) void attn21_kernel(
    const unsigned short* __restrict__ Qp, const unsigned short* __restrict__ Kpk,
    const unsigned short* __restrict__ Vpk, const unsigned int* __restrict__ mbits,
    float* __restrict__ outp, float* __restrict__ attnp) {
  __shared__ float rsred[8][16];
  __shared__ float rinv16[16];
  __shared__ char uni[8][4224];

  const int bx = blockIdx.x;
  const int c  = bx & 7;
  const int s  = bx >> 3;
  const int j  = s & 3;
  const int qt = s >> 2;
  const int bh = c * 4 + j;
  const int b  = bh >> 4, h = bh & 15;
  const int q0 = qt << 4;

  const int w = threadIdx.x >> 6, l = threadIdx.x & 63;
  const int lr = l & 15, lg = l >> 4;
  const int kw0 = w << 8;

  const float scale = 0.125f;
  const f32x4 fz = {0.f, 0.f, 0.f, 0.f};

  const unsigned short* Qh = Qp + (size_t)(b * S_LEN + q0 + lr) * DM + h * 64;
  const bf16x8 qf0 = *(const bf16x8*)(Qh + lg * 8);
  const bf16x8 qf1 = *(const bf16x8*)(Qh + 32 + lg * 8);

  const unsigned short* Kw = Kpk + (size_t)((b * 16 + h) * 128 + w * 16) * 1024;

  const unsigned int* mbr = mbits + ((size_t)(b * S_LEN + q0 + lr) << 6) + (kw0 >> 5);
  const ui32x4 mwa = *(const ui32x4*)(mbr);
  const ui32x4 mwb = *(const ui32x4*)(mbr + 4);

  unsigned int pkA[16], pkB[16];
  float rs = 0.f;
#pragma unroll
  for (int i = 0; i < 16; ++i) {
    const bf16x8 ka0 = *(const bf16x8*)(Kw + i * 1024 + l * 8);
    const bf16x8 ka1 = *(const bf16x8*)(Kw + i * 1024 + 512 + l * 8);
    f32x4 sc = fz;
    sc = __builtin_amdgcn_mfma_f32_16x16x32_bf16(ka0, qf0, sc, 0, 0, 0);
    sc = __builtin_amdgcn_mfma_f32_16x16x32_bf16(ka1, qf1, sc, 0, 0, 0);
    const unsigned int wsel = (i < 8) ? mwa[i >> 1] : mwb[(i - 8) >> 1];
    const unsigned int nib = (wsel >> ((i & 1) * 16 + lg * 4)) & 15u;
    const float e0 = __expf((nib & 1u) ? sc[0] * scale : NEGV);
    const float e1 = __expf((nib & 2u) ? sc[1] * scale : NEGV);
    const float e2 = __expf((nib & 4u) ? sc[2] * scale : NEGV);
    const float e3 = __expf((nib & 8u) ? sc[3] * scale : NEGV);
    rs += (e0 + e1) + (e2 + e3);
    pkA[i] = pack_bf2(e0, e1);
    pkB[i] = pack_bf2(e2, e3);
  }
  rs += __shfl_xor(rs, 16, 64);
  rs += __shfl_xor(rs, 32, 64);
  if (l < 16) rsred[w][l] = rs;
  __syncthreads();
  if (threadIdx.x < 16) {
    float s0 = 0.f;
#pragma unroll
    for (int ww = 0; ww < 8; ++ww) s0 += rsred[ww][threadIdx.x];
    rinv16[threadIdx.x] = 1.0f / s0;
  }
  __syncthreads();

  const unsigned short* Vw = Vpk + ((size_t)(b * 16 + h) * 256 + w * 32) * 512;
  unsigned short* pbase = (unsigned short*)uni[w];

  f32x4 oacc[4];
#pragma unroll
  for (int n = 0; n < 4; ++n) oacc[n] = fz;

  // ---- PV loop: loads + LDS repack + MFMA only ----
#pragma unroll
  for (int pr = 0; pr < 4; ++pr) {
    unsigned short* pb = pbase + (pr & 1) * 1056;

    bf16x8 vbr[2][4];
#pragma unroll
    for (int s2 = 0; s2 < 2; ++s2)
#pragma unroll
      for (int n = 0; n < 4; ++n)
        vbr[s2][n] = *(const bf16x8*)(Vw + (size_t)(((pr * 2 + s2) * 4) + n) * 512 + l * 8);

#pragma unroll
    for (int s2 = 0; s2 < 2; ++s2) {
      const int wi = pr * 2 + s2;
      const u32x2 wv0 = {pkA[2 * wi],     pkB[2 * wi]};
      const u32x2 wv1 = {pkA[2 * wi + 1], pkB[2 * wi + 1]};
      *(u32x2*)(pb + lr * 66 + s2 * 32 + lg * 4) = wv0;
      *(u32x2*)(pb + lr * 66 + s2 * 32 + 16 + lg * 4) = wv1;
    }
#pragma unroll
    for (int s2 = 0; s2 < 2; ++s2) {
      const bf16x8 pa = *(const bf16x8*)(pb + lr * 66 + s2 * 32 + lg * 8);
#pragma unroll
      for (int n = 0; n < 4; ++n)
        oacc[n] = __builtin_amdgcn_mfma_f32_16x16x32_bf16(pa, vbr[s2][n], oacc[n], 0, 0, 0);
    }
  }

  // ---- store phase: 2 halves, per-wave [16][132] transpose, 2x512B NT per instr ----
  asm volatile("s_waitcnt lgkmcnt(0)" ::: "memory");
  float rv8[8];
#pragma unroll
  for (int jj = 0; jj < 8; ++jj) rv8[jj] = rinv16[(l >> 5) + 2 * jj];
  float* attnR = attnp + (size_t)((b * 16 + h) * S_LEN + q0) * S_LEN + kw0;
#pragma unroll
  for (int sh = 0; sh < 2; ++sh) {
#pragma unroll
    for (int i8 = 0; i8 < 8; ++i8) {
      const int i = sh * 8 + i8;
      const u32x2 wv = {pkA[i], pkB[i]};
      *(u32x2*)(pbase + lr * 132 + i8 * 16 + lg * 4) = wv;
    }
    asm volatile("s_waitcnt lgkmcnt(0)" ::: "memory");
#pragma unroll
    for (int jj = 0; jj < 8; ++jj) {
      const int row = (l >> 5) + 2 * jj;
      const us4 p4 = *(const us4*)(pbase + row * 132 + (l & 31) * 4);
      const float rv = rv8[jj];
      const f32x4 st = {__uint_as_float((unsigned)p4[0] << 16) * rv,
                        __uint_as_float((unsigned)p4[1] << 16) * rv,
                        __uint_as_float((unsigned)p4[2] << 16) * rv,
                        __uint_as_float((unsigned)p4[3] << 16) * rv};
      __builtin_nontemporal_store(st, (f32x4*)(attnR + (size_t)row * S_LEN + sh * 128 + (l & 31) * 4));
    }
    asm volatile("s_waitcnt lgkmcnt(0)" ::: "memory");
  }

  // ---- cross-wave out reduction ----
  float* outred = (float*)uni[w];
#pragma unroll
  for (int n = 0; n < 4; ++n)
#pragma unroll
    for (int jj = 0; jj < 4; ++jj)
      outred[(lg * 4 + jj) * 64 + n * 16 + lr] = oacc[n][jj];
  __syncthreads();
  if (threadIdx.x < 256) {
    const int q = threadIdx.x >> 4;
    const int d0 = (threadIdx.x & 15) * 4;
    const float rq = rinv16[q];
    float4 o = {0.f, 0.f, 0.f, 0.f};
#pragma unroll
    for (int ww = 0; ww < 8; ++ww) {
      const f32x4 sv = *(const f32x4*)((const float*)uni[ww] + q * 64 + d0);
      o.x += sv[0]; o.y += sv[1]; o.z += sv[2]; o.w += sv[3];
    }
    o.x *= rq; o.y *= rq; o.z *= rq; o.w *= rq;
    *(float4*)(outp + (size_t)(b * S_LEN + q0 + q) * DM + h * 64 + d0) = o;
  }
}

extern "C" void kernel_launch(void* const* d_in, const int* in_sizes, int n_in,
                              void* d_out, int out_size, void* d_ws, size_t ws_size,
                              hipStream_t stream) {
  const float* query = (const float*)d_in[0];
  const float* key_  = (const float*)d_in[1];
  const float* value = (const float*)d_in[2];
  const int*   mask  = (const int*)d_in[3];
  const float* Wq = (const float*)d_in[4];
  const float* bq = (const float*)d_in[5];
  const float* Wk = (const float*)d_in[6];
  const float* bk = (const float*)d_in[7];
  const float* Wv = (const float*)d_in[8];
  const float* bv = (const float*)d_in[9];

  float* outp  = (float*)d_out;
  float* attnp = outp + (size_t)2 * S_LEN * DM;

  unsigned short* ws  = (unsigned short*)d_ws;
  unsigned short* qbf = ws;
  unsigned short* kbf = qbf + 4194304;
  unsigned short* vbf = kbf + 4194304;
  unsigned short* wqb = vbf + 4194304;
  unsigned short* wkb = wqb + 1048576;
  unsigned short* wvb = wkb + 1048576;
  unsigned short* qp  = wvb + 1048576;
  unsigned short* kpk = qp + 4194304;
  unsigned short* vpk = kpk + 4194304;
  unsigned int*   mb  = (unsigned int*)(vpk + 4194304);

  prep_kernel<<<16384, 256, 0, stream>>>(query, key_, value, Wq, Wk, Wv, mask,
                                         qbf, kbf, vbf, wqb, wkb, wvb, mb);
  proj_gemm<<<768, 256, 0, stream>>>(qbf, wqb, bq, qp,
                                     kbf, wkb, bk, kpk,
                                     vbf, wvb, bv, vpk);
  attn21_kernel<<<4096, 512, 0, stream>>>(qp, kpk, vpk, mb, outp, attnp);
}